// Round 3
// baseline (361.805 us; speedup 1.0000x reference)
//
#include <hip/hip_runtime.h>

// Alias-free activation: up×2 (K=12 kaiser-sinc) -> lrelu(0.1) -> down×2.
// x: (8,128,32768) fp32; filters: 12 fp32 each; out: (8,128,32768) fp32.
//
// Derived direct form (verified vs reference in R0/R1, absmax 1.6e-2):
//   up[2t]   = 2 * sum_j fu[2j]   * xc[t-3+j],  j=0..5
//   up[2t+1] = 2 * sum_j fu[2j+1] * xc[t-2+j],  j=0..5
//   act[n]   = lrelu(up[n])
//   out[t]   = sum_k fd[k] * act[clamp(2t+k-5, 0, 2L-1)], k=0..11
// where xc = edge-clamped x.
//
// R1: dropped LDS (R0: 1.9e7 bank-conflict cycles). ~100 -> ~76 us.
// R2: OPT 8->16 (load amplification 3x->2x, 8 loads in flight/thread),
//     nontemporal float4 stores (out never re-read; keep L2/L3 for x).

#define LROW   32768
#define OPT    16
#define BLOCK  256
#define TILE   (OPT * BLOCK)   // 4096 outputs per block
#define KS     12
#define SLOPE  0.1f

typedef float f32x4 __attribute__((ext_vector_type(4)));

__global__ __launch_bounds__(BLOCK) void aa_act_kernel(
    const float* __restrict__ x,
    const float* __restrict__ upf,
    const float* __restrict__ dnf,
    float* __restrict__ out)
{
    const int tid = threadIdx.x;
    const int t   = blockIdx.x * TILE + OPT * tid;     // first output of this thread
    const size_t row = blockIdx.y;
    const float* __restrict__ xrow = x + row * (size_t)LROW;
    float* __restrict__ orow       = out + row * (size_t)LROW;

    // Wave-uniform filter values -> SGPRs. Fold the reference's `r *` (=2)
    // factor into fu.
    float fu[KS], fd[KS];
#pragma unroll
    for (int k = 0; k < KS; ++k) {
        fu[k] = 2.0f * upf[k];
        fd[k] = dnf[k];
    }

    // ---- Per-thread x window: xv[m] = xc[t-8+m], m in [0,32) ----
    const int base_g = t - 8;                           // 32B-aligned
    float xv[32];
    if (base_g >= 0 && base_g + 32 <= LROW) {
        const f32x4* __restrict__ src = reinterpret_cast<const f32x4*>(xrow + base_g);
#pragma unroll
        for (int q = 0; q < 8; ++q) {
            f32x4 w = src[q];
            xv[4*q+0] = w.x; xv[4*q+1] = w.y; xv[4*q+2] = w.z; xv[4*q+3] = w.w;
        }
    } else {
        // Only the first thread of row-block 0 and the last thread take this.
#pragma unroll
        for (int m = 0; m < 32; ++m) {
            int g = base_g + m;
            g = g < 0 ? 0 : (g >= LROW ? LROW - 1 : g);
            xv[m] = xrow[g];
        }
    }

    // ---- 42 act values in registers: a[e] = act(2t-5+e), e in [0,42) ----
    float a[42];
#pragma unroll
    for (int d = -2; d <= 18; ++d) {      // even up samples: n = 2(t+d), e = 2d+5
        float v = 0.0f;
#pragma unroll
        for (int j = 0; j < 6; ++j) v = fmaf(fu[2*j], xv[d + 5 + j], v);
        a[2*d + 5] = v >= 0.0f ? v : SLOPE * v;
    }
#pragma unroll
    for (int d = -3; d <= 17; ++d) {      // odd up samples: n = 2(t+d)+1, e = 2d+6
        float v = 0.0f;
#pragma unroll
        for (int j = 0; j < 6; ++j) v = fmaf(fu[2*j + 1], xv[d + 6 + j], v);
        a[2*d + 6] = v >= 0.0f ? v : SLOPE * v;
    }

    // ---- Edge replication (reference edge-pads act before the down-conv).
    // Only threads t==0 and t==LROW-OPT need it.
    if (t == 0) {
        a[4] = a[5]; a[3] = a[5]; a[2] = a[5]; a[1] = a[5]; a[0] = a[5];
    }
    if (t == LROW - OPT) {
        a[37] = a[36]; a[38] = a[36]; a[39] = a[36]; a[40] = a[36]; a[41] = a[36];
    }

    // ---- Downsample: out[t+m] = sum_k fd[k] * a[2m+k] ----
    float o[OPT];
#pragma unroll
    for (int m = 0; m < OPT; ++m) {
        float acc = 0.0f;
#pragma unroll
        for (int k = 0; k < KS; ++k) acc = fmaf(fd[k], a[2*m + k], acc);
        o[m] = acc;
    }

    f32x4* po = reinterpret_cast<f32x4*>(orow + t);     // t % 16 == 0 -> 64B aligned
#pragma unroll
    for (int q = 0; q < 4; ++q) {
        f32x4 v = { o[4*q+0], o[4*q+1], o[4*q+2], o[4*q+3] };
        __builtin_nontemporal_store(v, po + q);
    }
}

extern "C" void kernel_launch(void* const* d_in, const int* in_sizes, int n_in,
                              void* d_out, int out_size, void* d_ws, size_t ws_size,
                              hipStream_t stream) {
    const float* x   = (const float*)d_in[0];
    const float* upf = (const float*)d_in[1];
    const float* dnf = (const float*)d_in[2];
    float* out = (float*)d_out;

    const int rows = in_sizes[0] / LROW;          // 8*128 = 1024
    dim3 grid(LROW / TILE, rows);                  // (8, 1024)
    aa_act_kernel<<<grid, dim3(BLOCK), 0, stream>>>(x, upf, dnf, out);
}

// Round 5
// 241.977 us; speedup vs baseline: 1.4952x; 1.4952x over previous
//
#include <hip/hip_runtime.h>

// Alias-free activation: up×2 (K=12 kaiser-sinc) -> lrelu(0.1) -> down×2.
// x: (8,128,32768) fp32; filters: 12 fp32 each; out: (8,128,32768) fp32.
//
// Derived direct form (verified vs reference in R0/R1, absmax 1.6e-2):
//   up[2t]   = 2 * sum_j fu[2j]   * xc[t-3+j],  j=0..5
//   up[2t+1] = 2 * sum_j fu[2j+1] * xc[t-2+j],  j=0..5
//   act[n]   = lrelu(up[n])
//   out[t]   = sum_k fd[k] * act[clamp(2t+k-5, 0, 2L-1)], k=0..11
// where xc = edge-clamped x.
//
// R1: dropped LDS (R0: 1.9e7 bank-conflict cycles). ~100 -> ~76 us.
// R2: OPT 8->16 + NONTEMPORAL stores -> REGRESSION (210 us): nt defeats L2
//     write-combining; 16B/lane at 64B stride leaked partial lines to HBM
//     (WRITE_SIZE 128 MB -> 333 MB). Lesson: nt store only when each
//     instruction writes full contiguous lines.
// R3: keep OPT=16, revert to normal cached float4 stores.
// R4: identical resubmit (R3 bench was a GPU-acquisition timeout, no data).

#define LROW   32768
#define OPT    16
#define BLOCK  256
#define TILE   (OPT * BLOCK)   // 4096 outputs per block
#define KS     12
#define SLOPE  0.1f

typedef float f32x4 __attribute__((ext_vector_type(4)));

__global__ __launch_bounds__(BLOCK) void aa_act_kernel(
    const float* __restrict__ x,
    const float* __restrict__ upf,
    const float* __restrict__ dnf,
    float* __restrict__ out)
{
    const int tid = threadIdx.x;
    const int t   = blockIdx.x * TILE + OPT * tid;     // first output of this thread
    const size_t row = blockIdx.y;
    const float* __restrict__ xrow = x + row * (size_t)LROW;
    float* __restrict__ orow       = out + row * (size_t)LROW;

    // Wave-uniform filter values -> SGPRs. Fold the reference's `r *` (=2)
    // factor into fu.
    float fu[KS], fd[KS];
#pragma unroll
    for (int k = 0; k < KS; ++k) {
        fu[k] = 2.0f * upf[k];
        fd[k] = dnf[k];
    }

    // ---- Per-thread x window: xv[m] = xc[t-8+m], m in [0,32) ----
    const int base_g = t - 8;                           // 32B-aligned
    float xv[32];
    if (base_g >= 0 && base_g + 32 <= LROW) {
        const f32x4* __restrict__ src = reinterpret_cast<const f32x4*>(xrow + base_g);
#pragma unroll
        for (int q = 0; q < 8; ++q) {
            f32x4 w = src[q];
            xv[4*q+0] = w.x; xv[4*q+1] = w.y; xv[4*q+2] = w.z; xv[4*q+3] = w.w;
        }
    } else {
        // Only the first thread of row-block 0 and the last thread take this.
#pragma unroll
        for (int m = 0; m < 32; ++m) {
            int g = base_g + m;
            g = g < 0 ? 0 : (g >= LROW ? LROW - 1 : g);
            xv[m] = xrow[g];
        }
    }

    // ---- 42 act values in registers: a[e] = act(2t-5+e), e in [0,42) ----
    float a[42];
#pragma unroll
    for (int d = -2; d <= 18; ++d) {      // even up samples: n = 2(t+d), e = 2d+5
        float v = 0.0f;
#pragma unroll
        for (int j = 0; j < 6; ++j) v = fmaf(fu[2*j], xv[d + 5 + j], v);
        a[2*d + 5] = v >= 0.0f ? v : SLOPE * v;
    }
#pragma unroll
    for (int d = -3; d <= 17; ++d) {      // odd up samples: n = 2(t+d)+1, e = 2d+6
        float v = 0.0f;
#pragma unroll
        for (int j = 0; j < 6; ++j) v = fmaf(fu[2*j + 1], xv[d + 6 + j], v);
        a[2*d + 6] = v >= 0.0f ? v : SLOPE * v;
    }

    // ---- Edge replication (reference edge-pads act before the down-conv).
    // Only threads t==0 and t==LROW-OPT need it.
    if (t == 0) {
        a[4] = a[5]; a[3] = a[5]; a[2] = a[5]; a[1] = a[5]; a[0] = a[5];
    }
    if (t == LROW - OPT) {
        a[37] = a[36]; a[38] = a[36]; a[39] = a[36]; a[40] = a[36]; a[41] = a[36];
    }

    // ---- Downsample: out[t+m] = sum_k fd[k] * a[2m+k] ----
    float o[OPT];
#pragma unroll
    for (int m = 0; m < OPT; ++m) {
        float acc = 0.0f;
#pragma unroll
        for (int k = 0; k < KS; ++k) acc = fmaf(fd[k], a[2*m + k], acc);
        o[m] = acc;
    }

    f32x4* po = reinterpret_cast<f32x4*>(orow + t);     // t % 16 == 0 -> 64B aligned
#pragma unroll
    for (int q = 0; q < 4; ++q) {
        po[q] = (f32x4){ o[4*q+0], o[4*q+1], o[4*q+2], o[4*q+3] };
    }
}

extern "C" void kernel_launch(void* const* d_in, const int* in_sizes, int n_in,
                              void* d_out, int out_size, void* d_ws, size_t ws_size,
                              hipStream_t stream) {
    const float* x   = (const float*)d_in[0];
    const float* upf = (const float*)d_in[1];
    const float* dnf = (const float*)d_in[2];
    float* out = (float*)d_out;

    const int rows = in_sizes[0] / LROW;          // 8*128 = 1024
    dim3 grid(LROW / TILE, rows);                  // (8, 1024)
    aa_act_kernel<<<grid, dim3(BLOCK), 0, stream>>>(x, upf, dnf, out);
}

// Round 6
// 231.260 us; speedup vs baseline: 1.5645x; 1.0463x over previous
//
#include <hip/hip_runtime.h>

// Alias-free activation: up×2 (K=12 kaiser-sinc) -> lrelu(0.1) -> down×2.
// x: (8,128,32768) fp32; filters: 12 fp32 each; out: (8,128,32768) fp32.
//
// Direct form (verified vs reference R0-R4, absmax 1.6e-2):
//   a[e] = lrelu(up(2t-5+e));  out[t+m] = sum_k fd[k]*a[2m+k]
//   even/odd up-samples share the window: for e=2i and e=2i+1 both read
//   xc[t-5+i+j] = xv[i+3+j], with taps fu[2j+1] / fu[2j] respectively.
//   lrelu is positively homogeneous -> the reference's r*(=2) factor is
//   applied once at the output (keeps filters as raw s_loads -> SGPRs).
//
// R1: dropped LDS (R0: 1.9e7 bank-conflict cycles). 100 -> ~76 us.
// R2: nt-stores REGRESSION (WRITE 128->333 MB: partial-line leak). Reverted.
// R4: OPT=16 = 90 us, worse than OPT=8 (~76): halved wave count. Counters:
//     VALU 28%, HBM 28%, Occ 41% -> latency-overlap failure.
// R5: OPT=4 (64K waves) + 2-tile pipeline per wave: 10 dwordx4 in flight
//     before first vmcnt wait; tile-B loads hide under tile-A compute.

#define LROW  32768
#define OPT   4
#define BLOCK 256
#define TILE  (OPT * BLOCK)      // 1024 outputs per tile
#define TPR   (LROW / TILE)      // 32 tiles per row
#define NITER 2
#define GX    (TPR / NITER)      // 16 blocks in x
#define KS    12
#define SLOPE 0.1f

typedef float f32x4 __attribute__((ext_vector_type(4)));

__device__ __forceinline__ void load_win(float xv[20], const float* __restrict__ xrow, int t)
{
    const int base = t - 8;                    // t%4==0 -> 16B aligned
    if (base >= 0 && base + 20 <= LROW) {
        const f32x4* __restrict__ src = reinterpret_cast<const f32x4*>(xrow + base);
#pragma unroll
        for (int q = 0; q < 5; ++q) {
            f32x4 w = src[q];
            xv[4*q+0] = w.x; xv[4*q+1] = w.y; xv[4*q+2] = w.z; xv[4*q+3] = w.w;
        }
    } else {
        // Only 2 threads per row edge take this path.
#pragma unroll
        for (int m = 0; m < 20; ++m) {
            int g = base + m;
            g = g < 0 ? 0 : (g >= LROW ? LROW - 1 : g);
            xv[m] = xrow[g];
        }
    }
}

__device__ __forceinline__ void compute_store(const float xv[20],
                                              const float fu[KS], const float fd[KS],
                                              float* __restrict__ orow, int t)
{
    // 18 act values: a[e] = lrelu(up(2t-5+e))/2, e in [0,18)
    float a[18];
#pragma unroll
    for (int i = 0; i < 9; ++i) {
        float vo = 0.0f, ve = 0.0f;
#pragma unroll
        for (int j = 0; j < 6; ++j) {
            const float xx = xv[i + 3 + j];
            vo = fmaf(fu[2*j + 1], xx, vo);    // a[2i]   (odd up-sample)
            ve = fmaf(fu[2*j],     xx, ve);    // a[2i+1] (even up-sample)
        }
        a[2*i]     = fmaxf(vo, SLOPE * vo);    // lrelu, slope<1
        a[2*i + 1] = fmaxf(ve, SLOPE * ve);
    }

    // Edge replication (reference edge-pads act before the down-conv).
    if (t == 0) {
        a[0] = a[5]; a[1] = a[5]; a[2] = a[5]; a[3] = a[5]; a[4] = a[5];
    }
    if (t == LROW - OPT) {
        a[13] = a[12]; a[14] = a[12]; a[15] = a[12]; a[16] = a[12]; a[17] = a[12];
    }

    // Downsample; fold the deferred 2x here (inline-const v_mul).
    float o[OPT];
#pragma unroll
    for (int m = 0; m < OPT; ++m) {
        float acc = 0.0f;
#pragma unroll
        for (int k = 0; k < KS; ++k) acc = fmaf(fd[k], a[2*m + k], acc);
        o[m] = 2.0f * acc;
    }
    *reinterpret_cast<f32x4*>(orow + t) = (f32x4){ o[0], o[1], o[2], o[3] };
}

__global__ __launch_bounds__(BLOCK) void aa_act_kernel(
    const float* __restrict__ x,
    const float* __restrict__ upf,
    const float* __restrict__ dnf,
    float* __restrict__ out)
{
    const int tid = threadIdx.x;
    const int bx  = blockIdx.x;
    const size_t row = blockIdx.y;
    const float* __restrict__ xrow = x + row * (size_t)LROW;
    float* __restrict__ orow       = out + row * (size_t)LROW;

    // Raw filter taps: uniform constant-offset reads -> s_load; FMA takes
    // one SGPR operand, so these cost no VGPRs.
    float fu[KS], fd[KS];
#pragma unroll
    for (int k = 0; k < KS; ++k) { fu[k] = upf[k]; fd[k] = dnf[k]; }

    const int tA = bx * TILE + OPT * tid;
    const int tB = (bx + GX) * TILE + OPT * tid;

    // Issue all 10 loads before any use: tile-B loads in flight during
    // tile-A compute (2-deep reg pipeline).
    float xvA[20], xvB[20];
    load_win(xvA, xrow, tA);
    load_win(xvB, xrow, tB);

    compute_store(xvA, fu, fd, orow, tA);
    compute_store(xvB, fu, fd, orow, tB);
}

extern "C" void kernel_launch(void* const* d_in, const int* in_sizes, int n_in,
                              void* d_out, int out_size, void* d_ws, size_t ws_size,
                              hipStream_t stream) {
    const float* x   = (const float*)d_in[0];
    const float* upf = (const float*)d_in[1];
    const float* dnf = (const float*)d_in[2];
    float* out = (float*)d_out;

    const int rows = in_sizes[0] / LROW;          // 8*128 = 1024
    dim3 grid(GX, rows);                           // (16, 1024)
    aa_act_kernel<<<grid, dim3(BLOCK), 0, stream>>>(x, upf, dnf, out);
}